// Round 1
// baseline (123.570 us; speedup 1.0000x reference)
//
#include <hip/hip_runtime.h>
#include <math.h>

#define BB 64
#define QQ 900
#define NN 30
#define C1 1001
#define NUMC 1000
#define QN (QQ * NN)            // 27000
#define NO_OBJ_W 0.1f

#define MTPB 1024               // match kernel block size
#define NPT ((QN + MTPB - 1) / MTPB)   // 27 entries per thread

// ---- persistent device scratch (fully rewritten every call) ----
__device__ float  g_C[BB * QN];          // cost matrices
__device__ float  g_logZ[BB * QQ];       // per-query logsumexp
__device__ float4 g_xyxy[BB * QQ];       // clipped pred boxes (xyxy)
__device__ int    g_tc[BB * QQ];         // target class per query
__device__ int    g_pi[BB * NN];         // matched query idx
__device__ int    g_ti[BB * NN];         // matched target idx
__device__ float4 g_partial[BB];         // per-batch (ce, l1, gl, _)

__device__ __forceinline__ float giou_f(float ax1, float ay1, float ax2, float ay2,
                                        float bx1, float by1, float bx2, float by2) {
    float ix1 = fmaxf(ax1, bx1), iy1 = fmaxf(ay1, by1);
    float ix2 = fminf(ax2, bx2), iy2 = fminf(ay2, by2);
    float iw = fmaxf(ix2 - ix1, 0.f), ih = fmaxf(iy2 - iy1, 0.f);
    float inter = iw * ih;
    float areaA = fmaxf(ax2 - ax1, 0.f) * fmaxf(ay2 - ay1, 0.f);
    float areaB = fmaxf(bx2 - bx1, 0.f) * fmaxf(by2 - by1, 0.f);
    float uni = areaA + areaB - inter;
    float iou = inter / fmaxf(uni, 1e-6f);
    float cx1 = fminf(ax1, bx1), cy1 = fminf(ay1, by1);
    float cx2 = fmaxf(ax2, bx2), cy2 = fmaxf(ay2, by2);
    float cw = fmaxf(cx2 - cx1, 0.f), ch = fmaxf(cy2 - cy1, 0.f);
    float ac = cw * ch;
    return iou - (ac - uni) / fmaxf(ac, 1e-6f);
}

// ---- K1: per-query softmax + cost matrix + tc init ----
__global__ __launch_bounds__(256) void cost_kernel(const float* __restrict__ logits,
                                                   const float* __restrict__ pboxes,
                                                   const int*   __restrict__ labels,
                                                   const float* __restrict__ tboxes) {
    int gwave = (blockIdx.x * blockDim.x + threadIdx.x) >> 6;  // global query idx
    int lane = threadIdx.x & 63;
    if (gwave >= BB * QQ) return;
    int b = gwave / QQ;

    const float* row = logits + (size_t)gwave * C1;
    float v[16];
#pragma unroll
    for (int i = 0; i < 16; ++i) {
        int idx = lane + i * 64;
        v[i] = (idx < C1) ? row[idx] : -INFINITY;
    }
    float mx = v[0];
#pragma unroll
    for (int i = 1; i < 16; ++i) mx = fmaxf(mx, v[i]);
#pragma unroll
    for (int off = 32; off; off >>= 1) mx = fmaxf(mx, __shfl_xor(mx, off));
    float s = 0.f;
#pragma unroll
    for (int i = 0; i < 16; ++i) {
        int idx = lane + i * 64;
        if (idx < C1) s += expf(v[i] - mx);
    }
#pragma unroll
    for (int off = 32; off; off >>= 1) s += __shfl_xor(s, off);
    float logZ = mx + logf(s);

    // pred box -> clipped xyxy (uniform across wave)
    const float* pb = pboxes + (size_t)gwave * 4;
    float cx = pb[0], cy = pb[1], w = pb[2], h = pb[3];
    float x1 = fminf(fmaxf(cx - 0.5f * w, 0.f), 1.f);
    float y1 = fminf(fmaxf(cy - 0.5f * h, 0.f), 1.f);
    float x2 = fminf(fmaxf(cx + 0.5f * w, 0.f), 1.f);
    float y2 = fminf(fmaxf(cy + 0.5f * h, 0.f), 1.f);

    if (lane == 0) {
        g_logZ[gwave] = logZ;
        g_xyxy[gwave] = make_float4(x1, y1, x2, y2);
        g_tc[gwave] = NUMC;     // default: no-object class
    }

    if (lane < NN) {
        int t = lane;
        int lab = labels[b * NN + t];
        float pcls = expf(row[lab] - logZ);
        const float* tb = tboxes + ((size_t)(b * NN + t)) * 4;
        float tx1 = tb[0], ty1 = tb[1], tx2 = tb[2], ty2 = tb[3];
        float l1 = fabsf(x1 - tx1) + fabsf(y1 - ty1) + fabsf(x2 - tx2) + fabsf(y2 - ty2);
        float g = giou_f(x1, y1, x2, y2, tx1, ty1, tx2, ty2);
        g_C[(size_t)gwave * NN + t] = 1.0f * (-pcls) + 5.0f * l1 + 2.0f * (-g);
    }
}

// ---- K2: greedy matcher, one block per batch ----
__global__ __launch_bounds__(MTPB) void match_kernel() {
    int b = blockIdx.x;
    int tid = threadIdx.x;
    const float* Cb = g_C + (size_t)b * QN;

    unsigned int ordv[NPT];
#pragma unroll
    for (int k = 0; k < NPT; ++k) {
        int e = tid + k * MTPB;
        if (e < QN) {
            unsigned u = __float_as_uint(Cb[e]);
            ordv[k] = (u & 0x80000000u) ? ~u : (u | 0x80000000u);  // order-preserving map
        } else {
            ordv[k] = 0xFFFFFFFFu;
        }
    }
    int r = tid % NN;   // e % 30 base

    __shared__ unsigned long long s_red[MTPB / 64];
    __shared__ int s_pq, s_pt;

    for (int it = 0; it < NN; ++it) {
        // scan: min over packed (ord<<32 | flat_index) -> np.argmin tie-break
        unsigned long long best = 0xFFFFFFFFFFFFFFFFull;
#pragma unroll
        for (int k = 0; k < NPT; ++k) {
            unsigned long long key =
                ((unsigned long long)ordv[k] << 32) | (unsigned)(tid + k * MTPB);
            best = (key < best) ? key : best;
        }
#pragma unroll
        for (int off = 32; off; off >>= 1) {
            unsigned long long o = __shfl_xor(best, off);
            best = (o < best) ? o : best;
        }
        int lane = tid & 63, w = tid >> 6;
        if (lane == 0) s_red[w] = best;
        __syncthreads();
        if (tid == 0) {
            unsigned long long rbest = s_red[0];
            for (int ww = 1; ww < MTPB / 64; ++ww)
                if (s_red[ww] < rbest) rbest = s_red[ww];
            int e = (int)(unsigned)rbest;
            int pq = e / NN, pt = e - pq * NN;
            g_pi[b * NN + it] = pq;
            g_ti[b * NN + it] = pt;
            s_pq = pq;
            s_pt = pt;
        }
        __syncthreads();
        int pq30 = s_pq * NN;
        int pt = s_pt;
#pragma unroll
        for (int k = 0; k < NPT; ++k) {
            int e = tid + k * MTPB;
            int t = r + (k * MTPB) % NN;
            t -= (t >= NN) ? NN : 0;
            if (((unsigned)(e - pq30) < (unsigned)NN) || (t == pt))
                ordv[k] = 0xFFFFFFFFu;
        }
    }
}

// ---- K3: scatter matched labels into tc ----
__global__ __launch_bounds__(256) void scatter_kernel(const int* __restrict__ labels) {
    int i = blockIdx.x * blockDim.x + threadIdx.x;
    if (i >= BB * NN) return;
    int b = i / NN;
    int pq = g_pi[i];
    int pt = g_ti[i];
    g_tc[b * QQ + pq] = labels[b * NN + pt];
}

// ---- K4: per-batch losses ----
__global__ __launch_bounds__(256) void loss_kernel(const float* __restrict__ logits,
                                                   const float* __restrict__ tboxes) {
    int b = blockIdx.x;
    int tid = threadIdx.x;

    float ce_num = 0.f, ce_den = 0.f;
    for (int q = tid; q < QQ; q += 256) {
        int tc = g_tc[b * QQ + q];
        float lg = logits[((size_t)(b * QQ + q)) * C1 + tc];
        float nll = g_logZ[b * QQ + q] - lg;
        float w = (tc == NUMC) ? NO_OBJ_W : 1.0f;
        ce_num += w * nll;
        ce_den += w;
    }
    float l1s = 0.f, gls = 0.f;
    if (tid < NN) {
        int pq = g_pi[b * NN + tid];
        int pt = g_ti[b * NN + tid];
        float4 p = g_xyxy[b * QQ + pq];
        const float* tb = tboxes + ((size_t)(b * NN + pt)) * 4;
        float tx1 = tb[0], ty1 = tb[1], tx2 = tb[2], ty2 = tb[3];
        l1s = fabsf(p.x - tx1) + fabsf(p.y - ty1) + fabsf(p.z - tx2) + fabsf(p.w - ty2);
        gls = 1.0f - giou_f(p.x, p.y, p.z, p.w, tx1, ty1, tx2, ty2);
    }

    __shared__ float s4[4][4];
    int lane = tid & 63, w = tid >> 6;
    float vals[4] = {ce_num, ce_den, l1s, gls};
#pragma unroll
    for (int v = 0; v < 4; ++v) {
        float x = vals[v];
#pragma unroll
        for (int off = 32; off; off >>= 1) x += __shfl_xor(x, off);
        if (lane == 0) s4[w][v] = x;
    }
    __syncthreads();
    if (tid == 0) {
        float cn = 0, cd = 0, ls = 0, gs = 0;
        for (int ww = 0; ww < 4; ++ww) {
            cn += s4[ww][0];
            cd += s4[ww][1];
            ls += s4[ww][2];
            gs += s4[ww][3];
        }
        g_partial[b] = make_float4(cn / cd, ls / (float)(NN * 4), gs / (float)NN, 0.f);
    }
}

// ---- K5: reduce over batches ----
__global__ __launch_bounds__(64) void final_kernel(float* __restrict__ out) {
    int b = threadIdx.x;  // 64 == BB
    float4 p = g_partial[b];
    float ce = p.x, l1 = p.y, gl = p.z;
#pragma unroll
    for (int off = 32; off; off >>= 1) {
        ce += __shfl_xor(ce, off);
        l1 += __shfl_xor(l1, off);
        gl += __shfl_xor(gl, off);
    }
    if (b == 0) {
        const float invB = 1.0f / (float)BB;
        ce *= invB; l1 *= invB; gl *= invB;
        out[0] = ce + 5.0f * l1 + 2.0f * gl;
        out[1] = ce;
        out[2] = l1;
        out[3] = gl;
    }
}

extern "C" void kernel_launch(void* const* d_in, const int* in_sizes, int n_in,
                              void* d_out, int out_size, void* d_ws, size_t ws_size,
                              hipStream_t stream) {
    const float* pred_logits = (const float*)d_in[0];
    const float* pred_boxes  = (const float*)d_in[1];
    const int*   tgt_labels  = (const int*)d_in[2];
    const float* tgt_boxes   = (const float*)d_in[3];
    float* out = (float*)d_out;

    // K1: one wave per query, 4 waves per block
    int nwaves = BB * QQ;
    cost_kernel<<<nwaves / 4, 256, 0, stream>>>(pred_logits, pred_boxes, tgt_labels, tgt_boxes);
    // K2: one block per batch
    match_kernel<<<BB, MTPB, 0, stream>>>();
    // K3: scatter matched labels
    scatter_kernel<<<(BB * NN + 255) / 256, 256, 0, stream>>>(tgt_labels);
    // K4: per-batch losses
    loss_kernel<<<BB, 256, 0, stream>>>(pred_logits, tgt_boxes);
    // K5: final reduce
    final_kernel<<<1, 64, 0, stream>>>(out);
}